// Round 6
// baseline (62.031 us; speedup 1.0000x reference)
//
#include <hip/hip_runtime.h>
#include <math.h>

#define BB 2048
#define T  200
#define H  64
#define H1 80
#define H2 40
#define BT (BB * T)          // 409600
#define TILE 128
#define NBLK (BT / TILE)     // 3200

typedef __attribute__((ext_vector_type(8))) short short8;
typedef __attribute__((ext_vector_type(4))) float floatx4;

// ws layout:
//   ushort region: W2T [48][104], then W1P [80][128]
//   float  region: QH [2048][80], then SC scores [2048][256]
#define WS_W2T_US 0
#define WS_W1P_US (48 * 104)                   // 4992
#define WS_US_END (WS_W1P_US + 80 * 128)       // 15232 ushorts = 30464 B (16B aligned)
#define WS_QH_F   (WS_US_END / 2)              // 7616 (float index)
#define WS_SC_F   (WS_QH_F + BB * H1)          // 171456

__device__ __forceinline__ unsigned short f2b(float x) {
    union { float f; unsigned u; } v; v.f = x;
    unsigned r = v.u + 0x7FFF + ((v.u >> 16) & 1);   // RNE (finite inputs only)
    return (unsigned short)(r >> 16);
}
__device__ __forceinline__ float b2f(unsigned short u) {
    union { unsigned u; float f; } v; v.u = ((unsigned)u) << 16;
    return v.f;
}

// ---------------- prep: weights -> bf16, qh[b][f] for all b ----------------
__global__ __launch_bounds__(256)
void prep_kernel(const float* __restrict__ W1, const float* __restrict__ W2,
                 const float* __restrict__ b1, const float* __restrict__ query,
                 float* __restrict__ ws) {
    int gid = blockIdx.x * 256 + threadIdx.x;      // 0 .. 163839
    unsigned short* wsu = (unsigned short*)ws;
    if (gid < 48 * 104) {                          // W2^T padded [g][k]
        int n = gid / 104, k = gid % 104;
        float v = (n < H2 && k < H1) ? W2[k * H2 + n] : 0.f;
        wsu[WS_W2T_US + gid] = f2b(v);
    }
    if (gid < H1 * 128) {                          // W' = [Wk - Wm ; Wp]  [f][k]
        int f = gid >> 7, k = gid & 127;
        float v = (k < 64) ? W1[(64 + k) * H1 + f] - W1[(128 + k) * H1 + f]
                           : W1[(192 + (k - 64)) * H1 + f];
        wsu[WS_W1P_US + gid] = f2b(v);
    }
    // qh[b][f] = b1[f] + q[b] @ (Wq + Wm)
    int b = gid / H1, f = gid - b * H1;
    const float* q = query + (size_t)b * H;
    float acc = b1[f];
    #pragma unroll 8
    for (int h = 0; h < H; ++h)
        acc += q[h] * (W1[h * H1 + f] + W1[(128 + h) * H1 + f]);
    ws[WS_QH_F + gid] = acc;
}

// ---------------- scores: GEMM over bt rows, 128-row tiles ----------------
__global__ __launch_bounds__(512, 6)
void score_kernel(const float* __restrict__ query,
                  const float* __restrict__ keys,
                  const float* __restrict__ b2,
                  const float* __restrict__ Wfc,
                  const float* __restrict__ bfc,
                  float* __restrict__ ws)
{
    // sAS: A-tile keys (128 rows x 64 ushort, swizzled; 16384 B) UNION
    //      per-wave hid scratch (8 x 16 x 104 ushort = 26624 B)
    __shared__ unsigned short sAS[13312];
    __shared__ unsigned short sB1[80 * 128];   // 20480 B, swizzled
    __shared__ unsigned short sQb[128];        // bf16 q rows for b0, b0+1
    __shared__ float sQh2[160];                // qh rows for b0, b0+1

    const int tid = threadIdx.x;
    const int wv = tid >> 6, ln = tid & 63;
    const int lrow = ln & 15;
    const int lk8 = (ln >> 4) * 8;
    const int bt0 = blockIdx.x * TILE;
    const int b0 = bt0 / T;
    const int bsplit = (b0 + 1) * T;
    const int bnext = (b0 + 1 < BB) ? b0 + 1 : b0;

    // ---- stage A-tile: keys f32 -> bf16 LDS (swizzled 16B chunks) ----
    const float4* kb4 = reinterpret_cast<const float4*>(keys) + (size_t)bt0 * (H / 4);
    #pragma unroll
    for (int kk = 0; kk < 4; ++kk) {
        int idx = tid + (kk << 9);                 // 0..2047
        float4 v = kb4[idx];
        int row = idx >> 4, seg = idx & 15;
        int chunk = seg >> 1, half = seg & 1;
        uint2 p;
        p.x = (unsigned)f2b(v.x) | ((unsigned)f2b(v.y) << 16);
        p.y = (unsigned)f2b(v.z) | ((unsigned)f2b(v.w) << 16);
        *reinterpret_cast<uint2*>(
            &sAS[row * 64 + ((chunk ^ (row & 7)) << 3) + (half << 2)]) = p;
    }
    // ---- stage B1' weights to LDS (swizzled) ----
    const uint4* w1p4 = reinterpret_cast<const uint4*>(
        (const unsigned short*)ws + WS_W1P_US);
    #pragma unroll
    for (int kk = 0; kk < 3; ++kk) {
        int i = tid + (kk << 9);
        if (i < 1280) {
            uint4 v = w1p4[i];
            int row = i >> 4, c = i & 15;
            *reinterpret_cast<uint4*>(&sB1[row * 128 + ((c ^ (row & 7)) << 3)]) = v;
        }
    }
    if (tid < 128) {                               // q rows as bf16
        int which = tid >> 6, h = tid & 63;
        int bq = which ? bnext : b0;
        sQb[tid] = f2b(query[(size_t)bq * H + h]);
    }
    if (tid < 160) {                               // qh rows
        int which = (tid >= 80), f = tid - which * 80;
        int bq = which ? bnext : b0;
        sQh2[tid] = ws[WS_QH_F + bq * H1 + f];
    }
    __syncthreads();

    // ---- hoist A k-frags; build q*k frags in-register ----
    const int mrow = wv * 16 + lrow;
    const int selL = (bt0 + mrow >= bsplit) ? 1 : 0;
    short8 af[2], af23[2];
    #pragma unroll
    for (int ks = 0; ks < 2; ++ks) {
        int c = ks * 4 + (ln >> 4);
        af[ks] = *reinterpret_cast<const short8*>(
            &sAS[mrow * 64 + ((c ^ (mrow & 7)) << 3)]);
        short8 aq = *reinterpret_cast<const short8*>(&sQb[selL * 64 + ks * 32 + lk8]);
        #pragma unroll
        for (int j = 0; j < 8; ++j)
            af23[ks][j] = (short)f2b(
                b2f((unsigned short)af[ks][j]) * b2f((unsigned short)aq[j]));
    }
    __syncthreads();   // all af reads done before scratch overwrites sAS

    // ---- per-wave hid scratch; zero K-pad cols 80..95 ----
    unsigned short* scr = &sAS[wv * 1664];
    {
        uint2 z; z.x = 0; z.y = 0;
        *reinterpret_cast<uint2*>(&scr[(ln >> 2) * 104 + 80 + (ln & 3) * 4]) = z;
    }

    // ---- stage 1: hid[16][80] = ReLU([k, q*k] @ W' + qh) ----
    const int rb = (ln >> 4) * 4;
    const int c0 = (ln >> 4);
    #pragma unroll
    for (int nt = 0; nt < 5; ++nt) {
        int brow = nt * 16 + lrow;
        floatx4 acc = {0.f, 0.f, 0.f, 0.f};
        short8 bf;
        bf = *reinterpret_cast<const short8*>(
            &sB1[brow * 128 + (((0 + c0) ^ (brow & 7)) << 3)]);
        acc = __builtin_amdgcn_mfma_f32_16x16x32_bf16(af[0], bf, acc, 0, 0, 0);
        bf = *reinterpret_cast<const short8*>(
            &sB1[brow * 128 + (((4 + c0) ^ (brow & 7)) << 3)]);
        acc = __builtin_amdgcn_mfma_f32_16x16x32_bf16(af[1], bf, acc, 0, 0, 0);
        bf = *reinterpret_cast<const short8*>(
            &sB1[brow * 128 + (((8 + c0) ^ (brow & 7)) << 3)]);
        acc = __builtin_amdgcn_mfma_f32_16x16x32_bf16(af23[0], bf, acc, 0, 0, 0);
        bf = *reinterpret_cast<const short8*>(
            &sB1[brow * 128 + (((12 + c0) ^ (brow & 7)) << 3)]);
        acc = __builtin_amdgcn_mfma_f32_16x16x32_bf16(af23[1], bf, acc, 0, 0, 0);
        #pragma unroll
        for (int r = 0; r < 4; ++r) {
            int sel = (bt0 + wv * 16 + rb + r >= bsplit) ? 1 : 0;
            float qh = sQh2[sel * 80 + nt * 16 + lrow];
            scr[(rb + r) * 104 + nt * 16 + lrow] = f2b(fmaxf(acc[r] + qh, 0.f));
        }
    }

    // ---- stage 2: scores = relu(hid @ W2 + b2) . Wfc (w2t frags via L1) ----
    const unsigned short* w2t = (const unsigned short*)ws + WS_W2T_US;
    float bfc0 = bfc[0];
    short8 a2[3];
    #pragma unroll
    for (int ks = 0; ks < 3; ++ks)
        a2[ks] = *reinterpret_cast<const short8*>(&scr[lrow * 104 + ks * 32 + lk8]);
    floatx4 vsum = {0.f, 0.f, 0.f, 0.f};
    #pragma unroll
    for (int nt = 0; nt < 3; ++nt) {
        int g = nt * 16 + lrow;
        float wf = (g < H2) ? Wfc[g] : 0.f;
        float bb = (g < H2) ? b2[g] : 0.f;
        floatx4 acc = {0.f, 0.f, 0.f, 0.f};
        #pragma unroll
        for (int ks = 0; ks < 3; ++ks) {
            short8 b2f8 = *reinterpret_cast<const short8*>(
                &w2t[g * 104 + ks * 32 + lk8]);
            acc = __builtin_amdgcn_mfma_f32_16x16x32_bf16(a2[ks], b2f8, acc, 0, 0, 0);
        }
        #pragma unroll
        for (int r = 0; r < 4; ++r)
            vsum[r] += fmaxf(acc[r] + bb, 0.f) * wf;
    }
    #pragma unroll
    for (int r = 0; r < 4; ++r) {
        vsum[r] += __shfl_xor(vsum[r], 1);
        vsum[r] += __shfl_xor(vsum[r], 2);
        vsum[r] += __shfl_xor(vsum[r], 4);
        vsum[r] += __shfl_xor(vsum[r], 8);
    }
    if (lrow == 0) {
        #pragma unroll
        for (int r = 0; r < 4; ++r) {
            int btR = bt0 + wv * 16 + rb + r;
            int bR = btR / T;
            int tR = btR - bR * T;
            ws[WS_SC_F + bR * 256 + tR] = (vsum[r] + bfc0) * 0.125f;
        }
    }
}

// ---------------- softmax + weighted key sum: one block per b ----------------
__global__ __launch_bounds__(256)
void attn_out_kernel(const float* __restrict__ keys,
                     const int* __restrict__ keys_length,
                     const float* __restrict__ ws,
                     float* __restrict__ out)
{
    __shared__ float sS[256];
    __shared__ float sRed[8];
    __shared__ float sOutp[4][64];
    const int b = blockIdx.x;
    const int tid = threadIdx.x;
    const int wv = tid >> 6, ln = tid & 63;
    const int len = keys_length[b];

    float s = -INFINITY;
    if (tid < len) s = ws[WS_SC_F + b * 256 + tid];
    float m = s;
    #pragma unroll
    for (int off = 32; off > 0; off >>= 1) m = fmaxf(m, __shfl_xor(m, off));
    if (ln == 0) sRed[wv] = m;
    __syncthreads();
    float mx = fmaxf(fmaxf(sRed[0], sRed[1]), fmaxf(sRed[2], sRed[3]));
    float e = (tid < len) ? __expf(s - mx) : 0.f;
    sS[tid] = e;
    float sum = e;
    #pragma unroll
    for (int off = 32; off > 0; off >>= 1) sum += __shfl_xor(sum, off);
    if (ln == 0) sRed[4 + wv] = sum;
    __syncthreads();
    float denom = (sRed[4] + sRed[5]) + (sRed[6] + sRed[7]);
    float inv = 1.f / denom;

    const float* kb = keys + (size_t)b * T * H;
    int h4 = (ln & 15) * 4;
    int tg = wv * 4 + (ln >> 4);      // 0..15, 13 t's each
    float4 a; a.x = a.y = a.z = a.w = 0.f;
    #pragma unroll
    for (int i = 0; i < 13; ++i) {
        int t = tg * 13 + i;
        if (t < T) {
            float w = sS[t];
            float4 kv = *reinterpret_cast<const float4*>(&kb[t * H + h4]);
            a.x += w * kv.x; a.y += w * kv.y; a.z += w * kv.z; a.w += w * kv.w;
        }
    }
    a.x += __shfl_xor(a.x, 16); a.y += __shfl_xor(a.y, 16);
    a.z += __shfl_xor(a.z, 16); a.w += __shfl_xor(a.w, 16);
    a.x += __shfl_xor(a.x, 32); a.y += __shfl_xor(a.y, 32);
    a.z += __shfl_xor(a.z, 32); a.w += __shfl_xor(a.w, 32);
    if (ln < 16) *reinterpret_cast<float4*>(&sOutp[wv][h4]) = a;
    __syncthreads();
    if (tid < H) {
        float o = (sOutp[0][tid] + sOutp[1][tid]) + (sOutp[2][tid] + sOutp[3][tid]);
        out[(size_t)b * H + tid] = o * inv;
    }
}

extern "C" void kernel_launch(void* const* d_in, const int* in_sizes, int n_in,
                              void* d_out, int out_size, void* d_ws, size_t ws_size,
                              hipStream_t stream) {
    const float* query       = (const float*)d_in[0];
    const float* keys        = (const float*)d_in[1];
    const int*   keys_length = (const int*)  d_in[2];
    const float* W1          = (const float*)d_in[3];
    const float* b1          = (const float*)d_in[4];
    const float* W2          = (const float*)d_in[5];
    const float* b2          = (const float*)d_in[6];
    const float* Wfc         = (const float*)d_in[7];
    const float* bfc         = (const float*)d_in[8];
    float* out = (float*)d_out;
    float* ws  = (float*)d_ws;

    prep_kernel<<<640, 256, 0, stream>>>(W1, W2, b1, query, ws);
    score_kernel<<<NBLK, 512, 0, stream>>>(query, keys, b2, Wfc, bfc, ws);
    attn_out_kernel<<<BB, 256, 0, stream>>>(keys, keys_length, ws, out);
}

// Round 7
// 60.585 us; speedup vs baseline: 1.0239x; 1.0239x over previous
//
#include <hip/hip_runtime.h>
#include <math.h>

#define BB 2048
#define T  200
#define H  64
#define H1 80
#define H2 40
#define BT (BB * T)          // 409600
#define TILE 128
#define NBLK (BT / TILE)     // 3200

typedef __attribute__((ext_vector_type(8))) short short8;
typedef __attribute__((ext_vector_type(4))) float floatx4;

// ws layout:
//   ushort region: W2T [48][104], then W1P [80][128]
//   float  region: QH [2048][80], SC scores [2048][256]
//   ushort region: KB bf16 keys [BT][64]
#define WS_W2T_US 0
#define WS_W1P_US (48 * 104)                   // 4992
#define WS_US_END (WS_W1P_US + 80 * 128)       // 15232 ushorts (16B aligned)
#define WS_QH_F   (WS_US_END / 2)              // 7616 (float index)
#define WS_SC_F   (WS_QH_F + BB * H1)          // 171456
#define WS_F_END  (WS_SC_F + BB * 256)         // 695744
#define WS_KB_US  (WS_F_END * 2)               // 1391488 (ushort index)

__device__ __forceinline__ unsigned short f2b(float x) {
    union { float f; unsigned u; } v; v.f = x;
    unsigned r = v.u + 0x7FFF + ((v.u >> 16) & 1);   // RNE (finite inputs only)
    return (unsigned short)(r >> 16);
}
__device__ __forceinline__ float b2f(unsigned short u) {
    union { unsigned u; float f; } v; v.u = ((unsigned)u) << 16;
    return v.f;
}

// ---------------- prep: weights -> bf16, qh[b][f] for all b ----------------
__global__ __launch_bounds__(256)
void prep_kernel(const float* __restrict__ W1, const float* __restrict__ W2,
                 const float* __restrict__ b1, const float* __restrict__ query,
                 float* __restrict__ ws) {
    int gid = blockIdx.x * 256 + threadIdx.x;      // 0 .. 163839
    unsigned short* wsu = (unsigned short*)ws;
    if (gid < 48 * 104) {                          // W2^T padded [g][k]
        int n = gid / 104, k = gid % 104;
        float v = (n < H2 && k < H1) ? W2[k * H2 + n] : 0.f;
        wsu[WS_W2T_US + gid] = f2b(v);
    }
    if (gid < H1 * 128) {                          // W' = [Wk - Wm ; Wp]  [f][k]
        int f = gid >> 7, k = gid & 127;
        float v = (k < 64) ? W1[(64 + k) * H1 + f] - W1[(128 + k) * H1 + f]
                           : W1[(192 + (k - 64)) * H1 + f];
        wsu[WS_W1P_US + gid] = f2b(v);
    }
    // qh[b][f] = b1[f] + q[b] @ (Wq + Wm)
    int b = gid / H1, f = gid - b * H1;
    const float* q = query + (size_t)b * H;
    float acc = b1[f];
    #pragma unroll 8
    for (int h = 0; h < H; ++h)
        acc += q[h] * (W1[h * H1 + f] + W1[(128 + h) * H1 + f]);
    ws[WS_QH_F + gid] = acc;
}

// ---------------- scores: GEMM over bt rows, 128-row tiles ----------------
__global__ __launch_bounds__(512, 6)
void score_kernel(const float* __restrict__ query,
                  const float* __restrict__ keys,
                  const float* __restrict__ b2,
                  const float* __restrict__ Wfc,
                  const float* __restrict__ bfc,
                  float* __restrict__ ws)
{
    // sAS: A-tile keys (128 rows x 64 ushort, swizzled; 16384 B) UNION
    //      per-wave hid scratch (8 x 16 x 104 ushort = 26624 B)
    __shared__ unsigned short sAS[13312];
    __shared__ unsigned short sB1[80 * 128];   // 20480 B, swizzled
    __shared__ unsigned short sQb[128];        // bf16 q rows for b0, b0+1
    __shared__ float sQh2[160];                // qh rows for b0, b0+1

    const int tid = threadIdx.x;
    const int wv = tid >> 6, ln = tid & 63;
    const int lrow = ln & 15;
    const int lk8 = (ln >> 4) * 8;
    const int bt0 = blockIdx.x * TILE;
    const int b0 = bt0 / T;
    const int bsplit = (b0 + 1) * T;
    const int bnext = (b0 + 1 < BB) ? b0 + 1 : b0;
    unsigned short* wsu = (unsigned short*)ws;

    // ---- stage A-tile: keys f32 -> bf16 LDS (swizzled) + bf16 spill to ws ----
    const float4* kb4 = reinterpret_cast<const float4*>(keys) + (size_t)bt0 * (H / 4);
    #pragma unroll
    for (int kk = 0; kk < 4; ++kk) {
        int idx = tid + (kk << 9);                 // 0..2047
        float4 v = kb4[idx];
        int row = idx >> 4, seg = idx & 15;
        int chunk = seg >> 1, half = seg & 1;
        uint2 p;
        p.x = (unsigned)f2b(v.x) | ((unsigned)f2b(v.y) << 16);
        p.y = (unsigned)f2b(v.z) | ((unsigned)f2b(v.w) << 16);
        *reinterpret_cast<uint2*>(
            &sAS[row * 64 + ((chunk ^ (row & 7)) << 3) + (half << 2)]) = p;
        *reinterpret_cast<uint2*>(
            &wsu[WS_KB_US + ((size_t)(bt0 + row)) * 64 + (seg << 2)]) = p;
    }
    // ---- stage B1' weights to LDS (swizzled) ----
    const uint4* w1p4 = reinterpret_cast<const uint4*>(
        (const unsigned short*)ws + WS_W1P_US);
    #pragma unroll
    for (int kk = 0; kk < 3; ++kk) {
        int i = tid + (kk << 9);
        if (i < 1280) {
            uint4 v = w1p4[i];
            int row = i >> 4, c = i & 15;
            *reinterpret_cast<uint4*>(&sB1[row * 128 + ((c ^ (row & 7)) << 3)]) = v;
        }
    }
    if (tid < 128) {                               // q rows as bf16
        int which = tid >> 6, h = tid & 63;
        int bq = which ? bnext : b0;
        sQb[tid] = f2b(query[(size_t)bq * H + h]);
    }
    if (tid < 160) {                               // qh rows
        int which = (tid >= 80), f = tid - which * 80;
        int bq = which ? bnext : b0;
        sQh2[tid] = ws[WS_QH_F + bq * H1 + f];
    }
    __syncthreads();

    // ---- hoist A k-frags; build q*k frags in-register ----
    const int mrow = wv * 16 + lrow;
    const int selL = (bt0 + mrow >= bsplit) ? 1 : 0;
    short8 af[2], af23[2];
    #pragma unroll
    for (int ks = 0; ks < 2; ++ks) {
        int c = ks * 4 + (ln >> 4);
        af[ks] = *reinterpret_cast<const short8*>(
            &sAS[mrow * 64 + ((c ^ (mrow & 7)) << 3)]);
        short8 aq = *reinterpret_cast<const short8*>(&sQb[selL * 64 + ks * 32 + lk8]);
        #pragma unroll
        for (int j = 0; j < 8; ++j)
            af23[ks][j] = (short)f2b(
                b2f((unsigned short)af[ks][j]) * b2f((unsigned short)aq[j]));
    }
    __syncthreads();   // all af reads done before scratch overwrites sAS

    // ---- per-wave hid scratch; zero K-pad cols 80..95 ----
    unsigned short* scr = &sAS[wv * 1664];
    {
        uint2 z; z.x = 0; z.y = 0;
        *reinterpret_cast<uint2*>(&scr[(ln >> 2) * 104 + 80 + (ln & 3) * 4]) = z;
    }

    // ---- stage 1: hid[16][80] = ReLU([k, q*k] @ W' + qh) ----
    const int rb = (ln >> 4) * 4;
    const int c0 = (ln >> 4);
    #pragma unroll
    for (int nt = 0; nt < 5; ++nt) {
        int brow = nt * 16 + lrow;
        floatx4 acc = {0.f, 0.f, 0.f, 0.f};
        short8 bf;
        bf = *reinterpret_cast<const short8*>(
            &sB1[brow * 128 + (((0 + c0) ^ (brow & 7)) << 3)]);
        acc = __builtin_amdgcn_mfma_f32_16x16x32_bf16(af[0], bf, acc, 0, 0, 0);
        bf = *reinterpret_cast<const short8*>(
            &sB1[brow * 128 + (((4 + c0) ^ (brow & 7)) << 3)]);
        acc = __builtin_amdgcn_mfma_f32_16x16x32_bf16(af[1], bf, acc, 0, 0, 0);
        bf = *reinterpret_cast<const short8*>(
            &sB1[brow * 128 + (((8 + c0) ^ (brow & 7)) << 3)]);
        acc = __builtin_amdgcn_mfma_f32_16x16x32_bf16(af23[0], bf, acc, 0, 0, 0);
        bf = *reinterpret_cast<const short8*>(
            &sB1[brow * 128 + (((12 + c0) ^ (brow & 7)) << 3)]);
        acc = __builtin_amdgcn_mfma_f32_16x16x32_bf16(af23[1], bf, acc, 0, 0, 0);
        #pragma unroll
        for (int r = 0; r < 4; ++r) {
            int sel = (bt0 + wv * 16 + rb + r >= bsplit) ? 1 : 0;
            float qh = sQh2[sel * 80 + nt * 16 + lrow];
            scr[(rb + r) * 104 + nt * 16 + lrow] = f2b(fmaxf(acc[r] + qh, 0.f));
        }
    }

    // ---- stage 2: scores = relu(hid @ W2 + b2) . Wfc (w2t frags via L1) ----
    const unsigned short* w2t = (const unsigned short*)ws + WS_W2T_US;
    float bfc0 = bfc[0];
    short8 a2[3];
    #pragma unroll
    for (int ks = 0; ks < 3; ++ks)
        a2[ks] = *reinterpret_cast<const short8*>(&scr[lrow * 104 + ks * 32 + lk8]);
    floatx4 vsum = {0.f, 0.f, 0.f, 0.f};
    #pragma unroll
    for (int nt = 0; nt < 3; ++nt) {
        int g = nt * 16 + lrow;
        float wf = (g < H2) ? Wfc[g] : 0.f;
        float bb = (g < H2) ? b2[g] : 0.f;
        floatx4 acc = {0.f, 0.f, 0.f, 0.f};
        #pragma unroll
        for (int ks = 0; ks < 3; ++ks) {
            short8 b2f8 = *reinterpret_cast<const short8*>(
                &w2t[g * 104 + ks * 32 + lk8]);
            acc = __builtin_amdgcn_mfma_f32_16x16x32_bf16(a2[ks], b2f8, acc, 0, 0, 0);
        }
        #pragma unroll
        for (int r = 0; r < 4; ++r)
            vsum[r] += fmaxf(acc[r] + bb, 0.f) * wf;
    }
    #pragma unroll
    for (int r = 0; r < 4; ++r) {
        vsum[r] += __shfl_xor(vsum[r], 1);
        vsum[r] += __shfl_xor(vsum[r], 2);
        vsum[r] += __shfl_xor(vsum[r], 4);
        vsum[r] += __shfl_xor(vsum[r], 8);
    }
    if (lrow == 0) {
        #pragma unroll
        for (int r = 0; r < 4; ++r) {
            int btR = bt0 + wv * 16 + rb + r;
            int bR = btR / T;
            int tR = btR - bR * T;
            ws[WS_SC_F + bR * 256 + tR] = (vsum[r] + bfc0) * 0.125f;
        }
    }
}

// ---------------- softmax + weighted key sum (bf16 keys from ws) ----------------
__global__ __launch_bounds__(256)
void attn_out_kernel(const int* __restrict__ keys_length,
                     const float* __restrict__ ws,
                     float* __restrict__ out)
{
    __shared__ float sS[256];
    __shared__ float sRed[8];
    __shared__ float sOutp[4][64];
    const int b = blockIdx.x;
    const int tid = threadIdx.x;
    const int wv = tid >> 6, ln = tid & 63;
    const int len = keys_length[b];

    float s = -INFINITY;
    if (tid < len) s = ws[WS_SC_F + b * 256 + tid];
    float m = s;
    #pragma unroll
    for (int off = 32; off > 0; off >>= 1) m = fmaxf(m, __shfl_xor(m, off));
    if (ln == 0) sRed[wv] = m;
    __syncthreads();
    float mx = fmaxf(fmaxf(sRed[0], sRed[1]), fmaxf(sRed[2], sRed[3]));
    float e = (tid < len) ? __expf(s - mx) : 0.f;
    sS[tid] = e;
    float sum = e;
    #pragma unroll
    for (int off = 32; off > 0; off >>= 1) sum += __shfl_xor(sum, off);
    if (ln == 0) sRed[4 + wv] = sum;
    __syncthreads();
    float denom = (sRed[4] + sRed[5]) + (sRed[6] + sRed[7]);
    float inv = 1.f / denom;

    // weighted key sum: lane = (row_grp, chunk); 8 rows x 8 chunks per wave
    const unsigned short* kbu = (const unsigned short*)ws + WS_KB_US + (size_t)b * T * 64;
    const int c = tid & 7;          // 8-bf16 chunk (h = c*8 .. c*8+7)
    const int rg = tid >> 3;        // 0..31 row group
    float acc[8];
    #pragma unroll
    for (int j = 0; j < 8; ++j) acc[j] = 0.f;
    #pragma unroll
    for (int k = 0; k < 7; ++k) {
        int t = rg + (k << 5);
        if (t < T) {
            float w = sS[t];
            uint4 v = *reinterpret_cast<const uint4*>(&kbu[t * 64 + c * 8]);
            acc[0] += w * b2f((unsigned short)(v.x & 0xffff));
            acc[1] += w * b2f((unsigned short)(v.x >> 16));
            acc[2] += w * b2f((unsigned short)(v.y & 0xffff));
            acc[3] += w * b2f((unsigned short)(v.y >> 16));
            acc[4] += w * b2f((unsigned short)(v.z & 0xffff));
            acc[5] += w * b2f((unsigned short)(v.z >> 16));
            acc[6] += w * b2f((unsigned short)(v.w & 0xffff));
            acc[7] += w * b2f((unsigned short)(v.w >> 16));
        }
    }
    #pragma unroll
    for (int j = 0; j < 8; ++j) {
        acc[j] += __shfl_xor(acc[j], 8);
        acc[j] += __shfl_xor(acc[j], 16);
        acc[j] += __shfl_xor(acc[j], 32);
    }
    if (ln < 8) {
        float4 v0, v1;
        v0.x = acc[0]; v0.y = acc[1]; v0.z = acc[2]; v0.w = acc[3];
        v1.x = acc[4]; v1.y = acc[5]; v1.z = acc[6]; v1.w = acc[7];
        *reinterpret_cast<float4*>(&sOutp[wv][ln * 8])     = v0;
        *reinterpret_cast<float4*>(&sOutp[wv][ln * 8 + 4]) = v1;
    }
    __syncthreads();
    if (tid < H) {
        float o = (sOutp[0][tid] + sOutp[1][tid]) + (sOutp[2][tid] + sOutp[3][tid]);
        out[(size_t)b * H + tid] = o * inv;
    }
}

extern "C" void kernel_launch(void* const* d_in, const int* in_sizes, int n_in,
                              void* d_out, int out_size, void* d_ws, size_t ws_size,
                              hipStream_t stream) {
    const float* query       = (const float*)d_in[0];
    const float* keys        = (const float*)d_in[1];
    const int*   keys_length = (const int*)  d_in[2];
    const float* W1          = (const float*)d_in[3];
    const float* b1          = (const float*)d_in[4];
    const float* W2          = (const float*)d_in[5];
    const float* b2          = (const float*)d_in[6];
    const float* Wfc         = (const float*)d_in[7];
    const float* bfc         = (const float*)d_in[8];
    float* out = (float*)d_out;
    float* ws  = (float*)d_ws;

    prep_kernel<<<640, 256, 0, stream>>>(W1, W2, b1, query, ws);
    score_kernel<<<NBLK, 512, 0, stream>>>(query, keys, b2, Wfc, bfc, ws);
    attn_out_kernel<<<BB, 256, 0, stream>>>(keys_length, ws, out);
}